// Round 4
// baseline (344.507 us; speedup 1.0000x reference)
//
#include <hip/hip_runtime.h>

#define B_ 64
#define L_ 196
#define D_ 2048
#define I_ 512
#define M_ (B_*L_)   // 12544

typedef __attribute__((ext_vector_type(8))) short bf16x8;
typedef __attribute__((ext_vector_type(4))) float f32x4;
typedef unsigned short u16;

__device__ __forceinline__ u16 f2bf(float x){
  unsigned u = __float_as_uint(x);
  u += 0x7fffu + ((u >> 16) & 1u);
  return (u16)(u >> 16);
}

__device__ __forceinline__ void gld16(const void* g, void* l){
  __builtin_amdgcn_global_load_lds(
      (const __attribute__((address_space(1))) void*)g,
      (__attribute__((address_space(3))) void*)l, 16, 0, 0);
}

// gfx9 waitcnt imm: vmcnt[3:0]=bits3:0, expcnt=bits6:4, lgkmcnt=bits11:8, vmcnt[5:4]=bits15:14
template<int N> __device__ __forceinline__ void wait_vm(){
  __builtin_amdgcn_s_waitcnt((N&15) | ((N&48)<<10) | (7<<4) | (15<<8));
}
__device__ __forceinline__ void wait_lgkm0(){
  __builtin_amdgcn_s_waitcnt(15 | (48<<10) | (7<<4));   // vmcnt=63 (no wait), lgkmcnt=0
}
__device__ __forceinline__ void bar(){
  asm volatile("" ::: "memory");
  __builtin_amdgcn_s_barrier();
  asm volatile("" ::: "memory");
}

// in: [R,C] fp32 row-major  ->  out: [C,R] bf16 row-major
__global__ void transpose_cvt_kernel(const float* __restrict__ in, u16* __restrict__ out, int R, int C){
  __shared__ float tile[32][33];
  int c0 = blockIdx.x*32, r0 = blockIdx.y*32;
  int tx = threadIdx.x, ty = threadIdx.y; // blockDim (32,8)
  for (int i=0;i<32;i+=8)
    tile[ty+i][tx] = in[(size_t)(r0+ty+i)*C + c0 + tx];
  __syncthreads();
  for (int i=0;i<32;i+=8)
    out[(size_t)(c0+ty+i)*R + r0 + tx] = f2bf(tile[tx][ty+i]);
}

// hs[b][n] = b_h[n] + sum_k hidden[b][k]*W_h[k][n].  k-split over 4 groups of 128.
__launch_bounds__(256)
__global__ void hs_kernel(const float* __restrict__ hidden, const float* __restrict__ Wh,
                          const float* __restrict__ bh, float* __restrict__ hs){
  __shared__ float red[4][64];
  const int nl = threadIdx.x & 63, kg = threadIdx.x >> 6;
  const int n = blockIdx.x*64 + nl, b = blockIdx.y;
  const float* hrow = hidden + b*I_;
  float a0=0.f, a1=0.f;
  #pragma unroll
  for (int k=kg*128; k<kg*128+128; k+=2){
    a0 = fmaf(hrow[k+0], Wh[(size_t)(k+0)*I_ + n], a0);
    a1 = fmaf(hrow[k+1], Wh[(size_t)(k+1)*I_ + n], a1);
  }
  red[kg][nl] = a0 + a1;
  __syncthreads();
  if (kg == 0)
    hs[b*I_ + n] = bh[n] + (red[0][nl]+red[1][nl]) + (red[2][nl]+red[3][nl]);
}

// GEMM1 (cvt fused): t = bf16(fv @ WfT^T + b_f + hs[batch])   [M,512]
// R4: BM=64, BN=64, BK=32 -> grid (8,196)=1568 blocks (6/CU resident, ~24 waves/CU)
// + XCD-chunked work remap: each XCD owns 196 consecutive x-major work items, so all
//   8 N-blocks of an A panel share that XCD's L2 (kills the 2x A over-fetch, and turns
//   wait_vm drains from HBM-latency into L2-latency).
// LDS 24 KB: Als 2x8KB fp32, Bls 2x4KB bf16.  3 loads/wave/tile (2A+1B), wait_vm<3>.
__launch_bounds__(256)
__global__ void gemm1_kernel(const float* __restrict__ A, const u16* __restrict__ Bt,
                             const float* __restrict__ bias, const float* __restrict__ hs,
                             u16* __restrict__ outb)
{
  constexpr int K = D_, BK = 32, NIT = K/BK;      // 64
  __shared__ __align__(16) float Als[2][64*32];   // 8 KB each
  __shared__ __align__(16) u16  Bls[2][64*32];    // 4 KB each

  const int tid = threadIdx.x, lane = tid&63, wave = tid>>6;
  // XCD-chunked remap (bijective: 1568 = 8*196)
  const int lid = blockIdx.y*8 + blockIdx.x;
  const int wid = (lid & 7)*196 + (lid >> 3);
  const int m0 = (wid >> 3)*64, n0 = (wid & 7)*64;
  const int q = lane>>4, mr = lane&15;
  const int wrow = (wave&1)*32, wcol = (wave>>1)*32;

  // A staging: 8 issues of 8 rows x 32 k (fp32, 1024B each); wave takes 2.
  // lane covers row j*8+(lane>>3); pre-swizzled global chunk = (lane&7)^(row&7)
  const int arow = lane>>3, achk = (lane&7)^arow;
  const float* Ag[2]; int Alo[2];
  #pragma unroll
  for (int u=0;u<2;++u){
    int j = wave*2+u;
    Ag[u] = A + (size_t)(m0 + j*8 + arow)*K + achk*4;
    Alo[u] = j*256;                               // float units
  }
  // B staging: 4 issues of 16 rows x 32 k (bf16, 1024B each); wave takes 1.
  const int brow = lane>>2, bchk = (lane&3)^(brow&3);
  const u16* Bg = Bt + (size_t)(n0 + wave*16 + brow)*K + bchk*8;
  const int  Blo = wave*512;                      // u16 units

  // read offsets (same XOR as the pre-swizzled writes)
  int afoff[2][2], bgoff[2];
  #pragma unroll
  for (int i2=0;i2<2;i2++)
    #pragma unroll
    for (int p=0;p<2;p++){
      int R = wrow + i2*16 + mr;
      afoff[i2][p] = R*32 + (((2*q+p) ^ (mr&7))*4);   // float units
    }
  #pragma unroll
  for (int j=0;j<2;j++){
    int C = wcol + j*16 + mr;
    bgoff[j] = C*32 + ((q ^ (mr&3))*8);               // u16 units
  }

  f32x4 acc[2][2];
  #pragma unroll
  for (int i=0;i<2;i++)
    #pragma unroll
    for (int j=0;j<2;j++) acc[i][j] = (f32x4){0.f,0.f,0.f,0.f};

  // preload tiles 0,1 (6 outstanding per wave; 3 per tile: 2A + 1B)
  #pragma unroll
  for (int u=0;u<2;++u) gld16(Ag[u],    &Als[0][Alo[u]]);
  gld16(Bg,    &Bls[0][Blo]);
  #pragma unroll
  for (int u=0;u<2;++u) gld16(Ag[u]+BK, &Als[1][Alo[u]]);
  gld16(Bg+BK, &Bls[1][Blo]);

  for (int it=0; it<NIT; ++it){
    if (it+1<NIT) wait_vm<3>(); else wait_vm<0>();   // drain ONLY tile it
    bar();
    const float* Ab = Als[it&1];
    const u16*   Bb = Bls[it&1];
    f32x4 a0[2], a1[2]; bf16x8 bg[2];
    #pragma unroll
    for (int i2=0;i2<2;i2++){
      a0[i2] = *(const f32x4*)(Ab + afoff[i2][0]);
      a1[i2] = *(const f32x4*)(Ab + afoff[i2][1]);
    }
    #pragma unroll
    for (int j=0;j<2;j++) bg[j] = *(const bf16x8*)(Bb + bgoff[j]);
    wait_lgkm0();      // frags in regs
    bar();             // buf[it&1] free
    if (it+2<NIT){
      int k0 = (it+2)*BK;
      #pragma unroll
      for (int u=0;u<2;++u) gld16(Ag[u]+k0, &Als[it&1][Alo[u]]);
      gld16(Bg+k0, &Bls[it&1][Blo]);
    }
    // fp32 -> bf16 fragment build (RNE, same numerics as before)
    bf16x8 af[2];
    #pragma unroll
    for (int i2=0;i2<2;i2++){
      #pragma unroll
      for (int e=0;e<4;e++){
        af[i2][e]   = (short)f2bf(a0[i2][e]);
        af[i2][4+e] = (short)f2bf(a1[i2][e]);
      }
    }
    #pragma unroll
    for (int i2=0;i2<2;i2++)
      #pragma unroll
      for (int j=0;j<2;j++)
        acc[i2][j] = __builtin_amdgcn_mfma_f32_16x16x32_bf16(af[i2], bg[j], acc[i2][j], 0,0,0);
  }

  #pragma unroll
  for (int i2=0;i2<2;i2++){
    #pragma unroll
    for (int j=0;j<2;j++){
      int gcol = n0 + wcol + j*16 + mr;
      float bcol = bias[gcol];
      #pragma unroll
      for (int r=0;r<4;r++){
        int grow = m0 + wrow + i2*16 + q*4 + r;
        int batch = grow / L_;
        outb[(size_t)grow*I_ + gcol] = f2bf(acc[i2][j][r] + bcol + hs[batch*I_ + gcol]);
      }
    }
  }
}

// Fused GEMM2 + softmax + z.  BN=64: block = (batch b, 64 e-cols), each wave owns 16 cols.
// Round-0 best-measured version (unchanged).
__launch_bounds__(256)
__global__ void gemm2_fused_kernel(const u16* __restrict__ T, const u16* __restrict__ Wa,
                                   const float* __restrict__ b_a, const float* __restrict__ fv,
                                   float* __restrict__ out)
{
  constexpr int K = I_, BK = 32, NIT = K/BK;     // 16
  __shared__ __align__(16) u16 Als[2][256*32];   // 16 KB each (rows 196..255 staged, masked)
  __shared__ __align__(16) u16 Bls[2][64*32];    // 4 KB each

  const int tid = threadIdx.x, lane = tid&63, wave = tid>>6;
  const int b = blockIdx.y, n0 = blockIdx.x*64;
  const int q = lane>>4, mr = lane&15;
  const int l16 = lane>>2, kc4 = (lane&3)^(l16&3);

  // A: 16 issues of 16 rows x 32 k; wave takes 4
  const u16* Ag[4]; int Alo[4];
  #pragma unroll
  for (int u=0;u<4;++u){
    int j = wave*4+u;
    int grow = b*L_ + j*16 + l16; if (grow > M_-1) grow = M_-1;   // clamp (masked later)
    Ag[u] = T + (size_t)grow*K + kc4*8; Alo[u] = j*512;
  }
  // B: 4 issues; wave takes 1
  const u16* Bg = Wa + (size_t)(n0 + wave*16 + l16)*K + kc4*8;
  const int  Blo = wave*512;

  const int abase = mr*32 + ((q ^ (mr&3))*8);    // + i*512 per frag
  const int col  = n0 + wave*16 + mr;            // this lane's e-column
  const int boff = (wave*16+mr)*32 + ((q ^ (mr&3))*8);

  f32x4 acc[13];
  #pragma unroll
  for (int i=0;i<13;i++) acc[i] = (f32x4){0,0,0,0};

  // preload tiles 0,1 (10 outstanding per wave)
  #pragma unroll
  for (int u=0;u<4;++u) gld16(Ag[u],    &Als[0][Alo[u]]);
  gld16(Bg,    &Bls[0][Blo]);
  #pragma unroll
  for (int u=0;u<4;++u) gld16(Ag[u]+BK, &Als[1][Alo[u]]);
  gld16(Bg+BK, &Bls[1][Blo]);

  for (int it=0; it<NIT; ++it){
    if (it+1<NIT) wait_vm<5>(); else wait_vm<0>();
    bar();
    const u16* Ab = Als[it&1];
    const u16* Bb = Bls[it&1];
    bf16x8 bg0 = *(const bf16x8*)(Bb + boff);
    bf16x8 af[13];
    #pragma unroll
    for (int i=0;i<13;++i) af[i] = *(const bf16x8*)(Ab + abase + i*512);
    wait_lgkm0();
    bar();
    if (it+2<NIT){
      int k0 = (it+2)*BK;
      #pragma unroll
      for (int u=0;u<4;++u) gld16(Ag[u]+k0, &Als[it&1][Alo[u]]);
      gld16(Bg+k0, &Bls[it&1][Blo]);
    }
    #pragma unroll
    for (int i=0;i<13;++i)
      acc[i] = __builtin_amdgcn_mfma_f32_16x16x32_bf16(af[i], bg0, acc[i], 0,0,0);
  }

  // ---- fused epilogue: e = acc + b_a; softmax over 196 rows; alpha + z ----
  const bool v12 = (q == 0);                     // frag 12: rows 192..195 valid only for q==0
  float bc = b_a[col];
  #pragma unroll
  for (int i=0;i<13;++i)
    #pragma unroll
    for (int r=0;r<4;++r) acc[i][r] += bc;

  float m = -3.4e38f;
  #pragma unroll
  for (int i=0;i<12;++i)
    #pragma unroll
    for (int r=0;r<4;++r) m = fmaxf(m, acc[i][r]);
  if (v12)
    #pragma unroll
    for (int r=0;r<4;++r) m = fmaxf(m, acc[12][r]);
  m = fmaxf(m, __shfl_xor(m, 16));
  m = fmaxf(m, __shfl_xor(m, 32));

  float s = 0.f;
  #pragma unroll
  for (int i=0;i<12;++i)
    #pragma unroll
    for (int r=0;r<4;++r){ float e = __expf(acc[i][r]-m); acc[i][r] = e; s += e; }
  if (v12)
    #pragma unroll
    for (int r=0;r<4;++r){ float e = __expf(acc[12][r]-m); acc[12][r] = e; s += e; }
  s += __shfl_xor(s, 16);
  s += __shfl_xor(s, 32);
  float inv = 1.f/s;

  float* alpha = out + (size_t)B_*D_ + (size_t)b*L_*D_;
  const float* fvb = fv + (size_t)b*L_*D_;
  float z = 0.f;
  #pragma unroll
  for (int i=0;i<13;++i){
    if (i < 12 || v12){
      #pragma unroll
      for (int r=0;r<4;++r){
        int row = i*16 + q*4 + r;               // < 196 when valid
        float a = acc[i][r] * inv;
        alpha[(size_t)row*D_ + col] = a;
        z = fmaf(a, fvb[(size_t)row*D_ + col], z);
      }
    }
  }
  z += __shfl_xor(z, 16);
  z += __shfl_xor(z, 32);
  if (q == 0) out[(size_t)b*D_ + col] = z;
}

extern "C" void kernel_launch(void* const* d_in, const int* in_sizes, int n_in,
                              void* d_out, int out_size, void* d_ws, size_t ws_size,
                              hipStream_t stream){
  (void)in_sizes; (void)n_in; (void)out_size; (void)ws_size;
  const float* fv     = (const float*)d_in[0];
  const float* hidden = (const float*)d_in[1];
  const float* W_f    = (const float*)d_in[2];
  const float* b_f    = (const float*)d_in[3];
  const float* W_h    = (const float*)d_in[4];
  const float* b_h    = (const float*)d_in[5];
  const float* W_a    = (const float*)d_in[6];
  const float* b_a    = (const float*)d_in[7];
  float* out = (float*)d_out;

  char* ws = (char*)d_ws;
  u16*   t_bf  = (u16*)ws;                     // 12,845,056 B
  u16*   WfT   = (u16*)(ws + 12845056);        //  2,097,152 B
  u16*   WaT   = (u16*)(ws + 14942208);        //  2,097,152 B
  float* hsbuf = (float*)(ws + 17039360);      //    131,072 B

  transpose_cvt_kernel<<<dim3(I_/32, D_/32), dim3(32,8), 0, stream>>>(W_f, WfT, D_, I_);
  transpose_cvt_kernel<<<dim3(D_/32, I_/32), dim3(32,8), 0, stream>>>(W_a, WaT, I_, D_);
  hs_kernel<<<dim3(I_/64, B_), 256, 0, stream>>>(hidden, W_h, b_h, hsbuf);

  gemm1_kernel<<<dim3(I_/64, M_/64), 256, 0, stream>>>(fv, WfT, b_f, hsbuf, t_bf);
  gemm2_fused_kernel<<<dim3(D_/64, B_), 256, 0, stream>>>(t_bf, WaT, b_a, fv, out);
}

// Round 5
// 343.917 us; speedup vs baseline: 1.0017x; 1.0017x over previous
//
#include <hip/hip_runtime.h>

#define B_ 64
#define L_ 196
#define D_ 2048
#define I_ 512
#define M_ (B_*L_)   // 12544

typedef __attribute__((ext_vector_type(8))) short bf16x8;
typedef __attribute__((ext_vector_type(4))) float f32x4;
typedef unsigned short u16;

__device__ __forceinline__ u16 f2bf(float x){
  unsigned u = __float_as_uint(x);
  u += 0x7fffu + ((u >> 16) & 1u);
  return (u16)(u >> 16);
}

__device__ __forceinline__ void gld16(const void* g, void* l){
  __builtin_amdgcn_global_load_lds(
      (const __attribute__((address_space(1))) void*)g,
      (__attribute__((address_space(3))) void*)l, 16, 0, 0);
}

// gfx9 waitcnt imm: vmcnt[3:0]=bits3:0, expcnt=bits6:4, lgkmcnt=bits11:8, vmcnt[5:4]=bits15:14
template<int N> __device__ __forceinline__ void wait_vm(){
  __builtin_amdgcn_s_waitcnt((N&15) | ((N&48)<<10) | (7<<4) | (15<<8));
}
__device__ __forceinline__ void wait_lgkm0(){
  __builtin_amdgcn_s_waitcnt(15 | (48<<10) | (7<<4));   // vmcnt=63 (no wait), lgkmcnt=0
}
__device__ __forceinline__ void bar(){
  asm volatile("" ::: "memory");
  __builtin_amdgcn_s_barrier();
  asm volatile("" ::: "memory");
}

// in: [R,C] fp32 row-major  ->  out: [C,R] bf16 row-major
__global__ void transpose_cvt_kernel(const float* __restrict__ in, u16* __restrict__ out, int R, int C){
  __shared__ float tile[32][33];
  int c0 = blockIdx.x*32, r0 = blockIdx.y*32;
  int tx = threadIdx.x, ty = threadIdx.y; // blockDim (32,8)
  for (int i=0;i<32;i+=8)
    tile[ty+i][tx] = in[(size_t)(r0+ty+i)*C + c0 + tx];
  __syncthreads();
  for (int i=0;i<32;i+=8)
    out[(size_t)(c0+ty+i)*R + r0 + tx] = f2bf(tile[tx][ty+i]);
}

// hs[b][n] = b_h[n] + sum_k hidden[b][k]*W_h[k][n].  k-split over 4 groups of 128.
__launch_bounds__(256)
__global__ void hs_kernel(const float* __restrict__ hidden, const float* __restrict__ Wh,
                          const float* __restrict__ bh, float* __restrict__ hs){
  __shared__ float red[4][64];
  const int nl = threadIdx.x & 63, kg = threadIdx.x >> 6;
  const int n = blockIdx.x*64 + nl, b = blockIdx.y;
  const float* hrow = hidden + b*I_;
  float a0=0.f, a1=0.f;
  #pragma unroll
  for (int k=kg*128; k<kg*128+128; k+=2){
    a0 = fmaf(hrow[k+0], Wh[(size_t)(k+0)*I_ + n], a0);
    a1 = fmaf(hrow[k+1], Wh[(size_t)(k+1)*I_ + n], a1);
  }
  red[kg][nl] = a0 + a1;
  __syncthreads();
  if (kg == 0)
    hs[b*I_ + n] = bh[n] + (red[0][nl]+red[1][nl]) + (red[2][nl]+red[3][nl]);
}

// GEMM1 (cvt fused): t = bf16(fv @ WfT^T + b_f + hs[batch])   [M,512]
// R5: BM=64, BN=64, BK=32, XCD-chunked remap (FETCH 204->62MB, measured R4), and the
// R4 bottleneck fix: fp32->bf16 via v_cvt_pk_bf16_f32 (1 inst / 2 elems, RNE — was a
// ~5-inst/elem integer path that made the kernel VALU-bound: VALUBusy 43% vs MfmaUtil 8.7%).
__launch_bounds__(256)
__global__ void gemm1_kernel(const float* __restrict__ A, const u16* __restrict__ Bt,
                             const float* __restrict__ bias, const float* __restrict__ hs,
                             u16* __restrict__ outb)
{
  constexpr int K = D_, BK = 32, NIT = K/BK;      // 64
  __shared__ __align__(16) float Als[2][64*32];   // 8 KB each
  __shared__ __align__(16) u16  Bls[2][64*32];    // 4 KB each

  const int tid = threadIdx.x, lane = tid&63, wave = tid>>6;
  // XCD-chunked remap (bijective: 1568 = 8*196)
  const int lid = blockIdx.y*8 + blockIdx.x;
  const int wid = (lid & 7)*196 + (lid >> 3);
  const int m0 = (wid >> 3)*64, n0 = (wid & 7)*64;
  const int q = lane>>4, mr = lane&15;
  const int wrow = (wave&1)*32, wcol = (wave>>1)*32;

  // A staging: 8 issues of 8 rows x 32 k (fp32, 1024B each); wave takes 2.
  // lane covers row j*8+(lane>>3); pre-swizzled global chunk = (lane&7)^(row&7)
  const int arow = lane>>3, achk = (lane&7)^arow;
  const float* Ag[2]; int Alo[2];
  #pragma unroll
  for (int u=0;u<2;++u){
    int j = wave*2+u;
    Ag[u] = A + (size_t)(m0 + j*8 + arow)*K + achk*4;
    Alo[u] = j*256;                               // float units
  }
  // B staging: 4 issues of 16 rows x 32 k (bf16, 1024B each); wave takes 1.
  const int brow = lane>>2, bchk = (lane&3)^(brow&3);
  const u16* Bg = Bt + (size_t)(n0 + wave*16 + brow)*K + bchk*8;
  const int  Blo = wave*512;                      // u16 units

  // read offsets (same XOR as the pre-swizzled writes)
  int afoff[2][2], bgoff[2];
  #pragma unroll
  for (int i2=0;i2<2;i2++)
    #pragma unroll
    for (int p=0;p<2;p++){
      int R = wrow + i2*16 + mr;
      afoff[i2][p] = R*32 + (((2*q+p) ^ (mr&7))*4);   // float units
    }
  #pragma unroll
  for (int j=0;j<2;j++){
    int C = wcol + j*16 + mr;
    bgoff[j] = C*32 + ((q ^ (mr&3))*8);               // u16 units
  }

  f32x4 acc[2][2];
  #pragma unroll
  for (int i=0;i<2;i++)
    #pragma unroll
    for (int j=0;j<2;j++) acc[i][j] = (f32x4){0.f,0.f,0.f,0.f};

  // preload tiles 0,1 (6 outstanding per wave; 3 per tile: 2A + 1B)
  #pragma unroll
  for (int u=0;u<2;++u) gld16(Ag[u],    &Als[0][Alo[u]]);
  gld16(Bg,    &Bls[0][Blo]);
  #pragma unroll
  for (int u=0;u<2;++u) gld16(Ag[u]+BK, &Als[1][Alo[u]]);
  gld16(Bg+BK, &Bls[1][Blo]);

  for (int it=0; it<NIT; ++it){
    if (it+1<NIT) wait_vm<3>(); else wait_vm<0>();   // drain ONLY tile it
    bar();
    const float* Ab = Als[it&1];
    const u16*   Bb = Bls[it&1];
    f32x4 a0[2], a1[2]; bf16x8 bg[2];
    #pragma unroll
    for (int i2=0;i2<2;i2++){
      a0[i2] = *(const f32x4*)(Ab + afoff[i2][0]);
      a1[i2] = *(const f32x4*)(Ab + afoff[i2][1]);
    }
    #pragma unroll
    for (int j=0;j<2;j++) bg[j] = *(const bf16x8*)(Bb + bgoff[j]);
    wait_lgkm0();      // frags in regs
    bar();             // buf[it&1] free
    if (it+2<NIT){
      int k0 = (it+2)*BK;
      #pragma unroll
      for (int u=0;u<2;++u) gld16(Ag[u]+k0, &Als[it&1][Alo[u]]);
      gld16(Bg+k0, &Bls[it&1][Blo]);
    }
    // fp32 -> bf16 via HW packed cvt (RNE): 4 insts per frag, 8 per iter.
    // bf16x8 reg j holds elems {2j (lo), 2j+1 (hi)} — matches cvt_pk output directly.
    bf16x8 af[2];
    #pragma unroll
    for (int i2=0;i2<2;i2++){
      union { unsigned u[4]; bf16x8 v; } cv;
      asm("v_cvt_pk_bf16_f32 %0, %1, %2" : "=v"(cv.u[0]) : "v"(a0[i2][0]), "v"(a0[i2][1]));
      asm("v_cvt_pk_bf16_f32 %0, %1, %2" : "=v"(cv.u[1]) : "v"(a0[i2][2]), "v"(a0[i2][3]));
      asm("v_cvt_pk_bf16_f32 %0, %1, %2" : "=v"(cv.u[2]) : "v"(a1[i2][0]), "v"(a1[i2][1]));
      asm("v_cvt_pk_bf16_f32 %0, %1, %2" : "=v"(cv.u[3]) : "v"(a1[i2][2]), "v"(a1[i2][3]));
      af[i2] = cv.v;
    }
    #pragma unroll
    for (int i2=0;i2<2;i2++)
      #pragma unroll
      for (int j=0;j<2;j++)
        acc[i2][j] = __builtin_amdgcn_mfma_f32_16x16x32_bf16(af[i2], bg[j], acc[i2][j], 0,0,0);
  }

  #pragma unroll
  for (int i2=0;i2<2;i2++){
    #pragma unroll
    for (int j=0;j<2;j++){
      int gcol = n0 + wcol + j*16 + mr;
      float bcol = bias[gcol];
      #pragma unroll
      for (int r=0;r<4;r++){
        int grow = m0 + wrow + i2*16 + q*4 + r;
        int batch = grow / L_;
        outb[(size_t)grow*I_ + gcol] = f2bf(acc[i2][j][r] + bcol + hs[batch*I_ + gcol]);
      }
    }
  }
}

// Fused GEMM2 + softmax + z.  BN=64: block = (batch b, 64 e-cols), each wave owns 16 cols.
// Round-0 best-measured version (unchanged).
__launch_bounds__(256)
__global__ void gemm2_fused_kernel(const u16* __restrict__ T, const u16* __restrict__ Wa,
                                   const float* __restrict__ b_a, const float* __restrict__ fv,
                                   float* __restrict__ out)
{
  constexpr int K = I_, BK = 32, NIT = K/BK;     // 16
  __shared__ __align__(16) u16 Als[2][256*32];   // 16 KB each (rows 196..255 staged, masked)
  __shared__ __align__(16) u16 Bls[2][64*32];    // 4 KB each

  const int tid = threadIdx.x, lane = tid&63, wave = tid>>6;
  const int b = blockIdx.y, n0 = blockIdx.x*64;
  const int q = lane>>4, mr = lane&15;
  const int l16 = lane>>2, kc4 = (lane&3)^(l16&3);

  // A: 16 issues of 16 rows x 32 k; wave takes 4
  const u16* Ag[4]; int Alo[4];
  #pragma unroll
  for (int u=0;u<4;++u){
    int j = wave*4+u;
    int grow = b*L_ + j*16 + l16; if (grow > M_-1) grow = M_-1;   // clamp (masked later)
    Ag[u] = T + (size_t)grow*K + kc4*8; Alo[u] = j*512;
  }
  // B: 4 issues; wave takes 1
  const u16* Bg = Wa + (size_t)(n0 + wave*16 + l16)*K + kc4*8;
  const int  Blo = wave*512;

  const int abase = mr*32 + ((q ^ (mr&3))*8);    // + i*512 per frag
  const int col  = n0 + wave*16 + mr;            // this lane's e-column
  const int boff = (wave*16+mr)*32 + ((q ^ (mr&3))*8);

  f32x4 acc[13];
  #pragma unroll
  for (int i=0;i<13;i++) acc[i] = (f32x4){0,0,0,0};

  // preload tiles 0,1 (10 outstanding per wave)
  #pragma unroll
  for (int u=0;u<4;++u) gld16(Ag[u],    &Als[0][Alo[u]]);
  gld16(Bg,    &Bls[0][Blo]);
  #pragma unroll
  for (int u=0;u<4;++u) gld16(Ag[u]+BK, &Als[1][Alo[u]]);
  gld16(Bg+BK, &Bls[1][Blo]);

  for (int it=0; it<NIT; ++it){
    if (it+1<NIT) wait_vm<5>(); else wait_vm<0>();
    bar();
    const u16* Ab = Als[it&1];
    const u16* Bb = Bls[it&1];
    bf16x8 bg0 = *(const bf16x8*)(Bb + boff);
    bf16x8 af[13];
    #pragma unroll
    for (int i=0;i<13;++i) af[i] = *(const bf16x8*)(Ab + abase + i*512);
    wait_lgkm0();
    bar();
    if (it+2<NIT){
      int k0 = (it+2)*BK;
      #pragma unroll
      for (int u=0;u<4;++u) gld16(Ag[u]+k0, &Als[it&1][Alo[u]]);
      gld16(Bg+k0, &Bls[it&1][Blo]);
    }
    #pragma unroll
    for (int i=0;i<13;++i)
      acc[i] = __builtin_amdgcn_mfma_f32_16x16x32_bf16(af[i], bg0, acc[i], 0,0,0);
  }

  // ---- fused epilogue: e = acc + b_a; softmax over 196 rows; alpha + z ----
  const bool v12 = (q == 0);                     // frag 12: rows 192..195 valid only for q==0
  float bc = b_a[col];
  #pragma unroll
  for (int i=0;i<13;++i)
    #pragma unroll
    for (int r=0;r<4;++r) acc[i][r] += bc;

  float m = -3.4e38f;
  #pragma unroll
  for (int i=0;i<12;++i)
    #pragma unroll
    for (int r=0;r<4;++r) m = fmaxf(m, acc[i][r]);
  if (v12)
    #pragma unroll
    for (int r=0;r<4;++r) m = fmaxf(m, acc[12][r]);
  m = fmaxf(m, __shfl_xor(m, 16));
  m = fmaxf(m, __shfl_xor(m, 32));

  float s = 0.f;
  #pragma unroll
  for (int i=0;i<12;++i)
    #pragma unroll
    for (int r=0;r<4;++r){ float e = __expf(acc[i][r]-m); acc[i][r] = e; s += e; }
  if (v12)
    #pragma unroll
    for (int r=0;r<4;++r){ float e = __expf(acc[12][r]-m); acc[12][r] = e; s += e; }
  s += __shfl_xor(s, 16);
  s += __shfl_xor(s, 32);
  float inv = 1.f/s;

  float* alpha = out + (size_t)B_*D_ + (size_t)b*L_*D_;
  const float* fvb = fv + (size_t)b*L_*D_;
  float z = 0.f;
  #pragma unroll
  for (int i=0;i<13;++i){
    if (i < 12 || v12){
      #pragma unroll
      for (int r=0;r<4;++r){
        int row = i*16 + q*4 + r;               // < 196 when valid
        float a = acc[i][r] * inv;
        alpha[(size_t)row*D_ + col] = a;
        z = fmaf(a, fvb[(size_t)row*D_ + col], z);
      }
    }
  }
  z += __shfl_xor(z, 16);
  z += __shfl_xor(z, 32);
  if (q == 0) out[(size_t)b*D_ + col] = z;
}

extern "C" void kernel_launch(void* const* d_in, const int* in_sizes, int n_in,
                              void* d_out, int out_size, void* d_ws, size_t ws_size,
                              hipStream_t stream){
  (void)in_sizes; (void)n_in; (void)out_size; (void)ws_size;
  const float* fv     = (const float*)d_in[0];
  const float* hidden = (const float*)d_in[1];
  const float* W_f    = (const float*)d_in[2];
  const float* b_f    = (const float*)d_in[3];
  const float* W_h    = (const float*)d_in[4];
  const float* b_h    = (const float*)d_in[5];
  const float* W_a    = (const float*)d_in[6];
  const float* b_a    = (const float*)d_in[7];
  float* out = (float*)d_out;

  char* ws = (char*)d_ws;
  u16*   t_bf  = (u16*)ws;                     // 12,845,056 B
  u16*   WfT   = (u16*)(ws + 12845056);        //  2,097,152 B
  u16*   WaT   = (u16*)(ws + 14942208);        //  2,097,152 B
  float* hsbuf = (float*)(ws + 17039360);      //    131,072 B

  transpose_cvt_kernel<<<dim3(I_/32, D_/32), dim3(32,8), 0, stream>>>(W_f, WfT, D_, I_);
  transpose_cvt_kernel<<<dim3(D_/32, I_/32), dim3(32,8), 0, stream>>>(W_a, WaT, I_, D_);
  hs_kernel<<<dim3(I_/64, B_), 256, 0, stream>>>(hidden, W_h, b_h, hsbuf);

  gemm1_kernel<<<dim3(I_/64, M_/64), 256, 0, stream>>>(fv, WfT, b_f, hsbuf, t_bf);
  gemm2_fused_kernel<<<dim3(D_/64, B_), 256, 0, stream>>>(t_bf, WaT, b_a, fv, out);
}

// Round 7
// 313.108 us; speedup vs baseline: 1.1003x; 1.0984x over previous
//
#include <hip/hip_runtime.h>

#define B_ 64
#define L_ 196
#define D_ 2048
#define I_ 512
#define M_ (B_*L_)   // 12544

typedef __attribute__((ext_vector_type(8))) short bf16x8;
typedef __attribute__((ext_vector_type(4))) float f32x4;
typedef unsigned short u16;

__device__ __forceinline__ u16 f2bf(float x){
  unsigned u = __float_as_uint(x);
  u += 0x7fffu + ((u >> 16) & 1u);
  return (u16)(u >> 16);
}

__device__ __forceinline__ void gld16(const void* g, void* l){
  __builtin_amdgcn_global_load_lds(
      (const __attribute__((address_space(1))) void*)g,
      (__attribute__((address_space(3))) void*)l, 16, 0, 0);
}

// gfx9 waitcnt imm: vmcnt[3:0]=bits3:0, expcnt=bits6:4, lgkmcnt=bits11:8, vmcnt[5:4]=bits15:14
template<int N> __device__ __forceinline__ void wait_vm(){
  __builtin_amdgcn_s_waitcnt((N&15) | ((N&48)<<10) | (7<<4) | (15<<8));
}
__device__ __forceinline__ void wait_lgkm0(){
  __builtin_amdgcn_s_waitcnt(15 | (48<<10) | (7<<4));   // vmcnt=63 (no wait), lgkmcnt=0
}
__device__ __forceinline__ void bar(){
  asm volatile("" ::: "memory");
  __builtin_amdgcn_s_barrier();
  asm volatile("" ::: "memory");
}

__device__ __forceinline__ unsigned cvtpk(float a, float b){
  unsigned r;
  asm("v_cvt_pk_bf16_f32 %0, %1, %2" : "=v"(r) : "v"(a), "v"(b));
  return r;
}

// in: [R,C] fp32 row-major  ->  out: [C,R] bf16 row-major
__global__ void transpose_cvt_kernel(const float* __restrict__ in, u16* __restrict__ out, int R, int C){
  __shared__ float tile[32][33];
  int c0 = blockIdx.x*32, r0 = blockIdx.y*32;
  int tx = threadIdx.x, ty = threadIdx.y; // blockDim (32,8)
  for (int i=0;i<32;i+=8)
    tile[ty+i][tx] = in[(size_t)(r0+ty+i)*C + c0 + tx];
  __syncthreads();
  for (int i=0;i<32;i+=8)
    out[(size_t)(c0+ty+i)*R + r0 + tx] = f2bf(tile[tx][ty+i]);
}

// hs[b][n] = b_h[n] + sum_k hidden[b][k]*W_h[k][n].  k-split over 4 groups of 128.
__launch_bounds__(256)
__global__ void hs_kernel(const float* __restrict__ hidden, const float* __restrict__ Wh,
                          const float* __restrict__ bh, float* __restrict__ hs){
  __shared__ float red[4][64];
  const int nl = threadIdx.x & 63, kg = threadIdx.x >> 6;
  const int n = blockIdx.x*64 + nl, b = blockIdx.y;
  const float* hrow = hidden + b*I_;
  float a0=0.f, a1=0.f;
  #pragma unroll
  for (int k=kg*128; k<kg*128+128; k+=2){
    a0 = fmaf(hrow[k+0], Wh[(size_t)(k+0)*I_ + n], a0);
    a1 = fmaf(hrow[k+1], Wh[(size_t)(k+1)*I_ + n], a1);
  }
  red[kg][nl] = a0 + a1;
  __syncthreads();
  if (kg == 0)
    hs[b*I_ + n] = bh[n] + (red[0][nl]+red[1][nl]) + (red[2][nl]+red[3][nl]);
}

// GEMM1 (cvt fused): t = bf16(fv @ WfT^T + b_f + hs[batch])   [M,512]
// R7 = R6 resubmission (container-level failure last round; kernel audit clean:
// bounds, barrier uniformity, swizzle write/read consistency, pipeline hazards all
// verified).  Structure: BM=128, BN=64, BK=64, NIT=32.  Full reg-staging: A fp32
// global->reg, cvt_pk to bf16 in regs, ds_write; B bf16 global->reg->ds_write.
// No global_load_lds => no async LDS writes => ONE barrier/iter (32 total, was 128
// in the R5 version that measured 4575 cyc/iter vs ~150 cyc of work).  16 MFMA
// per wave per iter (was 4).  LDS 48 KB -> 3 blocks/CU.  XCD-chunked remap kept
// (bijective: 784 = 8*98; R4 measured FETCH 204->62 MB from this).
__launch_bounds__(256)
__global__ void gemm1_kernel(const float* __restrict__ A, const u16* __restrict__ Bt,
                             const float* __restrict__ bias, const float* __restrict__ hs,
                             u16* __restrict__ outb)
{
  constexpr int K = D_, BK = 64, NIT = K/BK;      // 32
  __shared__ __align__(16) u16 Als[2][128*64];    // 16 KB each (bf16)
  __shared__ __align__(16) u16 Bls[2][64*64];     // 8 KB each

  const int tid = threadIdx.x, lane = tid&63, wave = tid>>6;
  const int lid = blockIdx.y*8 + blockIdx.x;      // 0..783
  const int wid = (lid & 7)*98 + (lid >> 3);      // XCD-chunked, bijective
  const int m0 = (wid >> 3)*128, n0 = (wid & 7)*64;
  const int q = lane>>4, mr = lane&15;
  const int wm = (wave&1)*64, wn = (wave>>1)*32;

  // ---- staging geometry ----
  // A: per wave 32 rows x 64 k fp32 = 8 loads of f32x4; lanes 0-15 = one row (256B).
  const int a_r  = wave*32 + (lane>>4);           // +4 per issue u
  const int a_kc = lane&15;                       // 4-float group (8B after cvt)
  const float* Aw = A + (size_t)(m0 + a_r)*K + a_kc*4;
  // B: per wave 16 rows x 64 k bf16 = 2 loads of bf16x8; 8 lanes = one row (128B).
  const int b_r  = wave*16 + (lane>>3);           // +8 per issue v
  const int b_kc = lane&7;                        // 16B chunk
  const u16* Bw = Bt + (size_t)(n0 + b_r)*K + b_kc*8;

  // LDS write offsets (u16 units), XOR-swizzled by row&7
  int awo[8], bwo[2];
  #pragma unroll
  for (int u=0;u<8;++u){
    int r = a_r + u*4;
    awo[u] = r*64 + (((a_kc>>1) ^ (r&7))*8) + (a_kc&1)*4;
  }
  #pragma unroll
  for (int v=0;v<2;++v){
    int r = b_r + v*8;
    bwo[v] = r*64 + ((b_kc ^ (r&7))*8);
  }

  // frag read offsets (u16 units); chunk = s*4+q of 8, swizzled by row&7
  int aro[2][4], bro[2][2];
  #pragma unroll
  for (int s=0;s<2;++s){
    #pragma unroll
    for (int i2=0;i2<4;++i2){
      int r = wm + i2*16 + mr;
      aro[s][i2] = r*64 + (((s*4+q) ^ (r&7))*8);
    }
    #pragma unroll
    for (int j=0;j<2;++j){
      int r = wn + j*16 + mr;
      bro[s][j] = r*64 + (((s*4+q) ^ (r&7))*8);
    }
  }

  f32x4 rA[8]; bf16x8 rB[2];
  f32x4 acc[4][2];
  #pragma unroll
  for (int i=0;i<4;++i)
    #pragma unroll
    for (int j=0;j<2;++j) acc[i][j] = (f32x4){0.f,0.f,0.f,0.f};

#define G1_LOAD(k0) { \
  _Pragma("unroll") \
  for (int u=0;u<8;++u) rA[u] = *(const f32x4*)(Aw + (size_t)(u*4)*K + (k0)); \
  _Pragma("unroll") \
  for (int v=0;v<2;++v) rB[v] = *(const bf16x8*)(Bw + (size_t)(v*8)*K + (k0)); }

#define G1_CVTWR(bi) { \
  u16* Ab_ = Als[bi]; u16* Bb_ = Bls[bi]; \
  _Pragma("unroll") \
  for (int u=0;u<8;++u){ \
    unsigned lo = cvtpk(rA[u][0], rA[u][1]); \
    unsigned hi = cvtpk(rA[u][2], rA[u][3]); \
    *(uint2*)(Ab_ + awo[u]) = make_uint2(lo, hi); \
  } \
  _Pragma("unroll") \
  for (int v=0;v<2;++v) *(bf16x8*)(Bb_ + bwo[v]) = rB[v]; }

  // prologue: tile0 -> regs -> LDS buf0; tile1 -> regs
  G1_LOAD(0)
  G1_CVTWR(0)
  G1_LOAD(BK)
  wait_lgkm0(); bar();

  for (int t=0; t<NIT; ++t){
    if (t+1 < NIT) G1_CVTWR((t+1)&1)      // consumes rA/rB (auto vmcnt wait)
    if (t+2 < NIT) G1_LOAD((t+2)*BK)      // refill regs for tile t+2
    const u16* Ab = Als[t&1];
    const u16* Bb = Bls[t&1];
    #pragma unroll
    for (int s=0;s<2;++s){
      bf16x8 af[4], bg[2];
      #pragma unroll
      for (int i2=0;i2<4;++i2) af[i2] = *(const bf16x8*)(Ab + aro[s][i2]);
      #pragma unroll
      for (int j=0;j<2;++j)    bg[j]  = *(const bf16x8*)(Bb + bro[s][j]);
      #pragma unroll
      for (int i2=0;i2<4;++i2)
        #pragma unroll
        for (int j=0;j<2;++j)
          acc[i2][j] = __builtin_amdgcn_mfma_f32_16x16x32_bf16(af[i2], bg[j], acc[i2][j], 0,0,0);
    }
    wait_lgkm0();      // ds_writes (and reads) drained before raw barrier
    bar();
  }

  #pragma unroll
  for (int i2=0;i2<4;++i2){
    #pragma unroll
    for (int j=0;j<2;++j){
      int gcol = n0 + wn + j*16 + mr;
      float bcol = bias[gcol];
      #pragma unroll
      for (int r=0;r<4;++r){
        int grow = m0 + wm + i2*16 + q*4 + r;
        int batch = grow / L_;
        outb[(size_t)grow*I_ + gcol] = f2bf(acc[i2][j][r] + bcol + hs[batch*I_ + gcol]);
      }
    }
  }
#undef G1_LOAD
#undef G1_CVTWR
}

// Fused GEMM2 + softmax + z.  BN=64: block = (batch b, 64 e-cols), each wave owns 16 cols.
// Round-0 best-measured version (unchanged).
__launch_bounds__(256)
__global__ void gemm2_fused_kernel(const u16* __restrict__ T, const u16* __restrict__ Wa,
                                   const float* __restrict__ b_a, const float* __restrict__ fv,
                                   float* __restrict__ out)
{
  constexpr int K = I_, BK = 32, NIT = K/BK;     // 16
  __shared__ __align__(16) u16 Als[2][256*32];   // 16 KB each (rows 196..255 staged, masked)
  __shared__ __align__(16) u16 Bls[2][64*32];    // 4 KB each

  const int tid = threadIdx.x, lane = tid&63, wave = tid>>6;
  const int b = blockIdx.y, n0 = blockIdx.x*64;
  const int q = lane>>4, mr = lane&15;
  const int l16 = lane>>2, kc4 = (lane&3)^(l16&3);

  // A: 16 issues of 16 rows x 32 k; wave takes 4
  const u16* Ag[4]; int Alo[4];
  #pragma unroll
  for (int u=0;u<4;++u){
    int j = wave*4+u;
    int grow = b*L_ + j*16 + l16; if (grow > M_-1) grow = M_-1;   // clamp (masked later)
    Ag[u] = T + (size_t)grow*K + kc4*8; Alo[u] = j*512;
  }
  // B: 4 issues; wave takes 1
  const u16* Bg = Wa + (size_t)(n0 + wave*16 + l16)*K + kc4*8;
  const int  Blo = wave*512;

  const int abase = mr*32 + ((q ^ (mr&3))*8);    // + i*512 per frag
  const int col  = n0 + wave*16 + mr;            // this lane's e-column
  const int boff = (wave*16+mr)*32 + ((q ^ (mr&3))*8);

  f32x4 acc[13];
  #pragma unroll
  for (int i=0;i<13;i++) acc[i] = (f32x4){0,0,0,0};

  // preload tiles 0,1 (10 outstanding per wave)
  #pragma unroll
  for (int u=0;u<4;++u) gld16(Ag[u],    &Als[0][Alo[u]]);
  gld16(Bg,    &Bls[0][Blo]);
  #pragma unroll
  for (int u=0;u<4;++u) gld16(Ag[u]+BK, &Als[1][Alo[u]]);
  gld16(Bg+BK, &Bls[1][Blo]);

  for (int it=0; it<NIT; ++it){
    if (it+1<NIT) wait_vm<5>(); else wait_vm<0>();
    bar();
    const u16* Ab = Als[it&1];
    const u16* Bb = Bls[it&1];
    bf16x8 bg0 = *(const bf16x8*)(Bb + boff);
    bf16x8 af[13];
    #pragma unroll
    for (int i=0;i<13;++i) af[i] = *(const bf16x8*)(Ab + abase + i*512);
    wait_lgkm0();
    bar();
    if (it+2<NIT){
      int k0 = (it+2)*BK;
      #pragma unroll
      for (int u=0;u<4;++u) gld16(Ag[u]+k0, &Als[it&1][Alo[u]]);
      gld16(Bg+k0, &Bls[it&1][Blo]);
    }
    #pragma unroll
    for (int i=0;i<13;++i)
      acc[i] = __builtin_amdgcn_mfma_f32_16x16x32_bf16(af[i], bg0, acc[i], 0,0,0);
  }

  // ---- fused epilogue: e = acc + b_a; softmax over 196 rows; alpha + z ----
  const bool v12 = (q == 0);                     // frag 12: rows 192..195 valid only for q==0
  float bc = b_a[col];
  #pragma unroll
  for (int i=0;i<13;++i)
    #pragma unroll
    for (int r=0;r<4;++r) acc[i][r] += bc;

  float m = -3.4e38f;
  #pragma unroll
  for (int i=0;i<12;++i)
    #pragma unroll
    for (int r=0;r<4;++r) m = fmaxf(m, acc[i][r]);
  if (v12)
    #pragma unroll
    for (int r=0;r<4;++r) m = fmaxf(m, acc[12][r]);
  m = fmaxf(m, __shfl_xor(m, 16));
  m = fmaxf(m, __shfl_xor(m, 32));

  float s = 0.f;
  #pragma unroll
  for (int i=0;i<12;++i)
    #pragma unroll
    for (int r=0;r<4;++r){ float e = __expf(acc[i][r]-m); acc[i][r] = e; s += e; }
  if (v12)
    #pragma unroll
    for (int r=0;r<4;++r){ float e = __expf(acc[12][r]-m); acc[12][r] = e; s += e; }
  s += __shfl_xor(s, 16);
  s += __shfl_xor(s, 32);
  float inv = 1.f/s;

  float* alpha = out + (size_t)B_*D_ + (size_t)b*L_*D_;
  const float* fvb = fv + (size_t)b*L_*D_;
  float z = 0.f;
  #pragma unroll
  for (int i=0;i<13;++i){
    if (i < 12 || v12){
      #pragma unroll
      for (int r=0;r<4;++r){
        int row = i*16 + q*4 + r;               // < 196 when valid
        float a = acc[i][r] * inv;
        alpha[(size_t)row*D_ + col] = a;
        z = fmaf(a, fvb[(size_t)row*D_ + col], z);
      }
    }
  }
  z += __shfl_xor(z, 16);
  z += __shfl_xor(z, 32);
  if (q == 0) out[(size_t)b*D_ + col] = z;
}

extern "C" void kernel_launch(void* const* d_in, const int* in_sizes, int n_in,
                              void* d_out, int out_size, void* d_ws, size_t ws_size,
                              hipStream_t stream){
  (void)in_sizes; (void)n_in; (void)out_size; (void)ws_size;
  const float* fv     = (const float*)d_in[0];
  const float* hidden = (const float*)d_in[1];
  const float* W_f    = (const float*)d_in[2];
  const float* b_f    = (const float*)d_in[3];
  const float* W_h    = (const float*)d_in[4];
  const float* b_h    = (const float*)d_in[5];
  const float* W_a    = (const float*)d_in[6];
  const float* b_a    = (const float*)d_in[7];
  float* out = (float*)d_out;

  char* ws = (char*)d_ws;
  u16*   t_bf  = (u16*)ws;                     // 12,845,056 B
  u16*   WfT   = (u16*)(ws + 12845056);        //  2,097,152 B
  u16*   WaT   = (u16*)(ws + 14942208);        //  2,097,152 B
  float* hsbuf = (float*)(ws + 17039360);      //    131,072 B

  transpose_cvt_kernel<<<dim3(I_/32, D_/32), dim3(32,8), 0, stream>>>(W_f, WfT, D_, I_);
  transpose_cvt_kernel<<<dim3(D_/32, I_/32), dim3(32,8), 0, stream>>>(W_a, WaT, I_, D_);
  hs_kernel<<<dim3(I_/64, B_), 256, 0, stream>>>(hidden, W_h, b_h, hsbuf);

  gemm1_kernel<<<dim3(8, M_/128), 256, 0, stream>>>(fv, WfT, b_f, hsbuf, t_bf);
  gemm2_fused_kernel<<<dim3(D_/64, B_), 256, 0, stream>>>(t_bf, WaT, b_a, fv, out);
}